// Round 7
// baseline (319.812 us; speedup 1.0000x reference)
//
#include <hip/hip_runtime.h>
#include <hip/hip_bf16.h>
#include <stdint.h>

#define NN 100000
#define NE 1600000
#define FDIM 128
#define NGRAPH 128
#define ODIM 16
#define NBKT 391                       // dst-buckets of 256 nodes
#define CAP 4608                       // record capacity per bucket (mean 4096, sd 64; +8 sigma)
#define PCAP 8704                      // padded csr stride: 4608 + 256*16 worst case
#define SCHUNK 4096                    // edges per k_scat block (512 thr x 8)
#define NSCAT ((NE + SCHUNK - 1) / SCHUNK)  // 391
#define NSTARTB ((NN + 255) / 256)     // 391

typedef __attribute__((ext_vector_type(8))) short short8;
typedef __attribute__((ext_vector_type(8))) unsigned short ushort8;
typedef __attribute__((ext_vector_type(4))) float f32x4;
typedef __attribute__((ext_vector_type(2))) float f32x2;
typedef __attribute__((ext_vector_type(4))) int i32x4;
typedef __attribute__((ext_vector_type(2))) int i32x2;

__device__ __forceinline__ float blo(unsigned int p) { return __uint_as_float(p << 16); }
__device__ __forceinline__ float bhi(unsigned int p) { return __uint_as_float(p & 0xffff0000u); }
__device__ __forceinline__ unsigned short f2b(float f) {
    unsigned int u = __float_as_uint(f);
    unsigned int r = (u + 0x7fffu + ((u >> 16) & 1u)) >> 16;
    return (unsigned short)r;
}
// packed RNE f32x2 -> bf16x2 (compiler emits v_cvt_pk_bf16_f32)
__device__ __forceinline__ unsigned int cvt2(float lo, float hi) {
    __hip_bfloat162 b = __float22bfloat162_rn(float2{lo, hi});
    return *reinterpret_cast<unsigned int*>(&b);
}

// runtime index-width detect: int64 inputs (values < 2^31) have all-zero odd
// int32 slots; random int32 node ids can't have 64 consecutive zero odd slots.
__device__ __forceinline__ int detect_w(const int* __restrict__ ei) {
    int lane = threadIdx.x & 63;
    int v = ei[2 * lane + 1];
    return (__ballot(v != 0) == 0ULL) ? 1 : 0;
}
__device__ __forceinline__ int ld_idx(const int* __restrict__ p, long long i, int w) {
    return w ? p[2 * i] : p[i];
}

// ---------------- prep: transposes + graph starts + cursors + zero-row ----------------
__global__ void __launch_bounds__(256) k_prep(
    const float* __restrict__ w1, const float* __restrict__ w2,
    unsigned short* __restrict__ wt1, unsigned short* __restrict__ wt2,
    const int* __restrict__ ei, const int* __restrict__ batch,
    int* __restrict__ gstart, int* __restrict__ bcursor,
    unsigned short* __restrict__ xws)
{
    int b = blockIdx.x, t = threadIdx.x;
    if (b < 128) {                       // both 128x128 transposes (fp32 -> bf16)
        int idx = b * 256 + t;           // 0..32767
        int which = idx >> 14, r = idx & 16383;
        int k = r >> 7, j = r & 127;
        const float* w = which ? w2 : w1;
        unsigned short* wt = which ? wt2 : wt1;
        wt[j * 128 + k] = f2b(w[k * 128 + j]);
    } else if (b < 128 + NSTARTB) {      // graph start offsets (batch sorted)
        int w = detect_w(ei);
        int i = (b - 128) * 256 + t;
        if (i < NN) {
            int bb = ld_idx(batch, i, w);
            int prev = (i == 0) ? -1 : ld_idx(batch, i - 1, w);
            for (int g = prev + 1; g <= bb; ++g) gstart[g] = i;
            if (i == NN - 1)
                for (int g = bb + 1; g <= NGRAPH; ++g) gstart[g] = NN;
        }
    } else {                             // cursor init + zero row NN of xws
        int i = (b - 128 - NSTARTB) * 256 + t;
        if (i < NBKT) bcursor[i] = i * CAP;
        if (b == 128 + NSTARTB && t < FDIM) xws[(size_t)NN * FDIM + t] = 0;
    }
}

// ---------------- scatter edges into fixed-stride dst-buckets (RANKED writes) --------
// record = src (17 bits) | (dst & 255) << 17
__global__ void __launch_bounds__(512) k_scat(const int* __restrict__ ei,
                                              int* __restrict__ bcursor,
                                              unsigned int* __restrict__ rec) {
    __shared__ int hist[NBKT];
    __shared__ int gbase[NBKT];
    __shared__ int lcur[NBKT];
    int t = threadIdx.x;
    int w = detect_w(ei);
    for (int i = t; i < NBKT; i += 512) hist[i] = 0;
    __syncthreads();
    long long e0 = (long long)blockIdx.x * SCHUNK;
    unsigned int myrec[8];
    int mybkt[8];
    #pragma unroll
    for (int j = 0; j < 8; ++j) {
        long long e = e0 + j * 512 + t;
        if (e < NE) {
            int s = ld_idx(ei, e, w);
            int d = ld_idx(ei, NE + e, w);
            mybkt[j] = d >> 8;
            myrec[j] = (unsigned int)s | ((unsigned int)(d & 255) << 17);
            atomicAdd(&hist[mybkt[j]], 1);
        } else mybkt[j] = -1;
    }
    __syncthreads();
    for (int i = t; i < NBKT; i += 512) {
        int c = hist[i];
        gbase[i] = c ? atomicAdd(&bcursor[i], c) : 0;
        lcur[i] = 0;
    }
    __syncthreads();
    #pragma unroll
    for (int j = 0; j < 8; ++j) {
        int b = mybkt[j];
        if (b >= 0) {
            int r = atomicAdd(&lcur[b], 1);
            int p = gbase[b] + r;
            if (p < (b + 1) * CAP) rec[p] = myrec[j];   // overflow guard (~never)
        }
    }
}

// ---------------- per-bucket counting sort -> padded csr + odeg + dinv ---------------
// csr holds BYTE offsets (src*256). Layout padded to 16-slot multiples per node;
// odeg.y = 4-padded REAL count (deg + self, rounded up to x4), so k_agg processes
// at most 3 sentinel slots per node. Self-loop slot at index deg; all other pad
// slots point at zero row NN.
__global__ void __launch_bounds__(256) k_bucket(const unsigned int* __restrict__ rec,
                                                const int* __restrict__ bcursor,
                                                int* __restrict__ csr,
                                                int2* __restrict__ odeg,
                                                float* __restrict__ dinv) {
    __shared__ unsigned int rbuf[CAP];
    __shared__ int srcout[PCAP];
    __shared__ int hist[256], scn[256], cur[256];
    int b = blockIdx.x, t = threadIdx.x;
    int rbase = b * CAP;
    int cnt = bcursor[b] - rbase;
    if (cnt > CAP) cnt = CAP;
    hist[t] = 0;
    __syncthreads();
    for (int j = t; j < cnt; j += 256) {
        unsigned int r = __builtin_nontemporal_load(&rec[rbase + j]);
        rbuf[j] = r;
        atomicAdd(&hist[r >> 17], 1);
    }
    for (int j = t; j < PCAP; j += 256) srcout[j] = NN << 8;   // sentinel = zero row
    __syncthreads();
    int node = (b << 8) + t;
    int v = hist[t];
    int pv = (node < NN) ? ((v + 16) & ~15) : 0;   // layout: +1 self slot, pad to 16
    scn[t] = pv;
    __syncthreads();
    for (int o = 1; o < 256; o <<= 1) {
        int tv = (t >= o) ? scn[t - o] : 0;
        __syncthreads();
        scn[t] += tv;
        __syncthreads();
    }
    int pexcl = scn[t] - pv;
    cur[t] = pexcl;
    int obase = b * PCAP;
    if (node < NN) {
        odeg[node] = make_int2(obase + pexcl, (v + 4) & ~3);  // 4-padded count incl self
        dinv[node] = rsqrtf((float)(v + 1));
        srcout[pexcl + v] = node << 8;                        // self-loop slot
    }
    __syncthreads();
    for (int j = t; j < cnt; j += 256) {
        unsigned int r = rbuf[j];
        int p = atomicAdd(&cur[r >> 17], 1);
        srcout[p] = (int)(r & 0x1FFFFu) << 8;        // pre-scaled byte offset
    }
    __syncthreads();
    int total = scn[255];
    for (int j = t; j < total; j += 256) csr[obase + j] = srcout[j];
}

// ---------------- GEMM: OUT[v][:] = bf16(dinv[v] * (X[v][:] @ W)) ----------------
#define LWS 136   // padded LDS row stride (bf16 elems)
template <bool BF16IN>
__global__ void __launch_bounds__(256) k_gemm(
    const void* __restrict__ Xv,            // [NN,128] fp32 or bf16
    const unsigned short* __restrict__ WT,  // [128,128] bf16, WT[j][k] = W[k][j]
    const float* __restrict__ dinv,
    unsigned short* __restrict__ OUT)       // [NN,128] bf16, scaled by dinv[row]
{
    __shared__ unsigned short lw[128 * LWS];
    int tid = threadIdx.x;
    for (int it = 0; it < 8; ++it) {
        int vidx = it * 256 + tid;
        int j = vidx >> 4, kc = vidx & 15;
        ushort8 v = *(const ushort8*)(WT + j * 128 + kc * 8);
        *(ushort8*)(&lw[j * LWS + kc * 8]) = v;
    }
    __syncthreads();

    int wave = tid >> 6, lane = tid & 63;
    int quad = lane >> 4, n16 = lane & 15;
    int row0 = (blockIdx.x * 4 + wave) * 16;
    if (row0 >= NN) return;   // NN % 16 == 0

    f32x4 acc[8];
    for (int ct = 0; ct < 8; ++ct) acc[ct] = (f32x4){0.f, 0.f, 0.f, 0.f};

    const int arow = row0 + n16;
    for (int kk = 0; kk < 4; ++kk) {
        short8 a;
        if (BF16IN) {
            a = *(const short8*)((const unsigned short*)Xv + (size_t)arow * 128 + kk * 32 + quad * 8);
        } else {
            const float* ap = (const float*)Xv + (size_t)arow * 128 + kk * 32 + quad * 8;
            f32x4 a01 = __builtin_nontemporal_load((const f32x4*)ap);
            f32x4 a23 = __builtin_nontemporal_load((const f32x4*)(ap + 4));
            uint4 P;
            P.x = cvt2(a01[0], a01[1]);
            P.y = cvt2(a01[2], a01[3]);
            P.z = cvt2(a23[0], a23[1]);
            P.w = cvt2(a23[2], a23[3]);
            a = *(short8*)&P;
        }
        for (int ct = 0; ct < 8; ++ct) {
            short8 b = *(const short8*)(&lw[(ct * 16 + n16) * LWS + kk * 32 + quad * 8]);
            acc[ct] = __builtin_amdgcn_mfma_f32_16x16x32_bf16(a, b, acc[ct], 0, 0, 0);
        }
    }
    // C/D layout: col = lane&15, row = quad*4 + reg
    for (int r = 0; r < 4; ++r) {
        int row = row0 + quad * 4 + r;
        float dv = dinv[row];
        for (int ct = 0; ct < 8; ++ct)
            OUT[(size_t)row * 128 + ct * 16 + n16] = f2b(acc[ct][r] * dv);
    }
}

// ---------------- aggregation: 4-granular padded csr, per-group loop bound ----------
// Lane = (edge slot group g 0..3, feature chunk f 0..15). csr/odeg/dinv loads and H
// stores are nontemporal (streaming) so the 25.6 MB xws gather table keeps L2.
__device__ __forceinline__ void acc8(f32x2* a2, uint4 q) {
    a2[0] += (f32x2){blo(q.x), bhi(q.x)};
    a2[1] += (f32x2){blo(q.y), bhi(q.y)};
    a2[2] += (f32x2){blo(q.z), bhi(q.z)};
    a2[3] += (f32x2){blo(q.w), bhi(q.w)};
}

__global__ void __launch_bounds__(256) k_agg(
    const unsigned short* __restrict__ XWS,   // [NN+1,128] bf16, row NN = zeros
    const int* __restrict__ csr,              // padded byte-offsets (src*256)
    const int2* __restrict__ odeg,            // {csr offset, 4-padded count incl self}
    const float* __restrict__ dinv,
    const float* __restrict__ bias,           // 128 fp32
    unsigned short* __restrict__ H)           // [NN,128] bf16
{
    int wave = threadIdx.x >> 6, lane = threadIdx.x & 63;
    int v = blockIdx.x * 4 + wave;             // NN % 4 == 0
    int g = lane >> 4, f = lane & 15;          // edge slot group, feature chunk (8 feats)
    i32x2 od = __builtin_nontemporal_load((const i32x2*)(odeg + v));
    int beg = od[0], pdeg4 = od[1];
    const char* xb = (const char*)XWS;
    unsigned fo = (unsigned)(f * 16);
    const int* cp = csr + beg + 4 * g;
    int lim = pdeg4 - 4 * g;                   // my group's loop bound

    f32x2 a2[4];
    a2[0] = (f32x2){0.f, 0.f}; a2[1] = (f32x2){0.f, 0.f};
    a2[2] = (f32x2){0.f, 0.f}; a2[3] = (f32x2){0.f, 0.f};

    for (int j = 0; j < lim; j += 16) {
        i32x4 c = __builtin_nontemporal_load((const i32x4*)(cp + j));
        uint4 q0 = *(const uint4*)(xb + ((unsigned)c.x + fo));
        uint4 q1 = *(const uint4*)(xb + ((unsigned)c.y + fo));
        uint4 q2 = *(const uint4*)(xb + ((unsigned)c.z + fo));
        uint4 q3 = *(const uint4*)(xb + ((unsigned)c.w + fo));
        acc8(a2, q0);
        acc8(a2, q1);
        acc8(a2, q2);
        acc8(a2, q3);
    }
    #pragma unroll
    for (int i = 0; i < 4; ++i) {
        a2[i].x += __shfl_xor(a2[i].x, 16);
        a2[i].y += __shfl_xor(a2[i].y, 16);
        a2[i].x += __shfl_xor(a2[i].x, 32);
        a2[i].y += __shfl_xor(a2[i].y, 32);
    }
    if (g == 0) {
        float dv = __builtin_nontemporal_load(dinv + v);
        float4 b0 = *(const float4*)(bias + f * 8);
        float4 b1 = *(const float4*)(bias + f * 8 + 4);
        i32x4 o;
        o[0] = (int)cvt2(fmaxf(fmaf(a2[0].x, dv, b0.x), 0.f), fmaxf(fmaf(a2[0].y, dv, b0.y), 0.f));
        o[1] = (int)cvt2(fmaxf(fmaf(a2[1].x, dv, b0.z), 0.f), fmaxf(fmaf(a2[1].y, dv, b0.w), 0.f));
        o[2] = (int)cvt2(fmaxf(fmaf(a2[2].x, dv, b1.x), 0.f), fmaxf(fmaf(a2[2].y, dv, b1.y), 0.f));
        o[3] = (int)cvt2(fmaxf(fmaf(a2[3].x, dv, b1.z), 0.f), fmaxf(fmaf(a2[3].y, dv, b1.w), 0.f));
        __builtin_nontemporal_store(o, (i32x4*)(H + (size_t)v * FDIM + f * 8));
    }
}

// ---------------- fused global mean pool + classifier (1024 thr, 16-way stripe) ------
__global__ void __launch_bounds__(1024) k_poolcls(
    const unsigned short* __restrict__ H, const int* __restrict__ gstart,
    const float* __restrict__ wc, const float* __restrict__ bc,
    float* __restrict__ out)
{
    __shared__ float red[2048];
    __shared__ float pl[FDIM];
    int g = blockIdx.x;
    int t = threadIdx.x;
    int pair = t & 63;
    int seg = t >> 6;                       // 0..15
    int beg = gstart[g], end = gstart[g + 1];
    float a0 = 0.f, a1 = 0.f;
    for (int i = beg + seg; i < end; i += 16) {
        unsigned int q = *(const unsigned int*)(H + (size_t)i * FDIM + 2 * pair);
        a0 += blo(q); a1 += bhi(q);
    }
    red[t] = a0; red[1024 + t] = a1;
    __syncthreads();
    if (seg == 0) {
        float s0 = 0.f, s1 = 0.f;
        #pragma unroll
        for (int k = 0; k < 16; ++k) {
            s0 += red[pair + 64 * k];
            s1 += red[1024 + pair + 64 * k];
        }
        float inv = 1.f / fmaxf((float)(end - beg), 1.f);
        pl[2 * pair] = s0 * inv;
        pl[2 * pair + 1] = s1 * inv;
    }
    __syncthreads();
    if (t < 256) {
        int o = t & 15, fs = t >> 4;
        float acc = 0.f;
        #pragma unroll
        for (int k = 0; k < 8; ++k)
            acc += pl[fs * 8 + k] * wc[(fs * 8 + k) * ODIM + o];
        red[t] = acc;
    }
    __syncthreads();
    if (t < 16) {
        float s = bc[t];
        #pragma unroll
        for (int k = 0; k < 16; ++k) s += red[k * 16 + t];
        out[g * ODIM + t] = s;
    }
}

extern "C" void kernel_launch(void* const* d_in, const int* in_sizes, int n_in,
                              void* d_out, int out_size, void* d_ws, size_t ws_size,
                              hipStream_t stream) {
    const float* x   = (const float*)d_in[0];
    const int* ei    = (const int*)d_in[1];
    const int* batch = (const int*)d_in[2];
    const float* w1  = (const float*)d_in[3];
    const float* b1  = (const float*)d_in[4];
    const float* w2  = (const float*)d_in[5];
    const float* b2  = (const float*)d_in[6];
    const float* wc  = (const float*)d_in[7];
    const float* bc  = (const float*)d_in[8];
    float* out = (float*)d_out;

    char* ws = (char*)d_ws;
    size_t off = 0;
    auto alloc = [&](size_t bytes) -> void* {
        off = (off + 255) & ~(size_t)255;
        void* p = ws + off;
        off += bytes;
        return p;
    };
    int*   bcursor = (int*)alloc(NBKT * 4);
    int2*  odeg    = (int2*)alloc((size_t)NN * 8);
    float* dinv    = (float*)alloc(NN * 4);
    int*   gstart  = (int*)alloc((NGRAPH + 1) * 4);
    unsigned int* rec = (unsigned int*)alloc((size_t)NBKT * CAP * 4);
    int*   csr     = (int*)alloc((size_t)NBKT * PCAP * 4 + 256);   // padded stride
    unsigned short* wt1 = (unsigned short*)alloc(128 * 128 * 2);
    unsigned short* wt2 = (unsigned short*)alloc(128 * 128 * 2);
    unsigned short* xws = (unsigned short*)alloc((size_t)(NN + 1) * FDIM * 2);  // +zero row
    unsigned short* h   = (unsigned short*)alloc((size_t)NN * FDIM * 2);

    k_prep<<<128 + NSTARTB + 2, 256, 0, stream>>>(w1, w2, wt1, wt2, ei, batch, gstart, bcursor, xws);
    k_scat<<<NSCAT, 512, 0, stream>>>(ei, bcursor, rec);
    k_bucket<<<NBKT, 256, 0, stream>>>(rec, bcursor, csr, odeg, dinv);

    // layer 1
    k_gemm<false><<<(NN / 16 + 3) / 4, 256, 0, stream>>>(x, wt1, dinv, xws);
    k_agg<<<NN / 4, 256, 0, stream>>>(xws, csr, odeg, dinv, b1, h);
    // layer 2
    k_gemm<true><<<(NN / 16 + 3) / 4, 256, 0, stream>>>(h, wt2, dinv, xws);
    k_agg<<<NN / 4, 256, 0, stream>>>(xws, csr, odeg, dinv, b2, h);
    // pool + classify (fused)
    k_poolcls<<<NGRAPH, 1024, 0, stream>>>(h, gstart, wc, bc, out);
}

// Round 8
// 306.414 us; speedup vs baseline: 1.0437x; 1.0437x over previous
//
#include <hip/hip_runtime.h>
#include <hip/hip_bf16.h>
#include <stdint.h>

#define NN 100000
#define NE 1600000
#define FDIM 128
#define NGRAPH 128
#define ODIM 16
#define NBKT 391                       // dst-buckets of 256 nodes
#define CAP 4608                       // record capacity per bucket (mean 4096, sd 64; +8 sigma)
#define PCAP 8704                      // padded csr stride: 4608 + 256*16 worst case
#define SCHUNK 4096                    // edges per k_scat block (512 thr x 8)
#define NSCAT ((NE + SCHUNK - 1) / SCHUNK)  // 391
#define NSTARTB ((NN + 255) / 256)     // 391

typedef __attribute__((ext_vector_type(8))) short short8;
typedef __attribute__((ext_vector_type(8))) unsigned short ushort8;
typedef __attribute__((ext_vector_type(4))) float f32x4;
typedef __attribute__((ext_vector_type(2))) float f32x2;

__device__ __forceinline__ float blo(unsigned int p) { return __uint_as_float(p << 16); }
__device__ __forceinline__ float bhi(unsigned int p) { return __uint_as_float(p & 0xffff0000u); }
__device__ __forceinline__ unsigned short f2b(float f) {
    unsigned int u = __float_as_uint(f);
    unsigned int r = (u + 0x7fffu + ((u >> 16) & 1u)) >> 16;
    return (unsigned short)r;
}
// packed RNE f32x2 -> bf16x2 (compiler emits v_cvt_pk_bf16_f32)
__device__ __forceinline__ unsigned int cvt2(float lo, float hi) {
    __hip_bfloat162 b = __float22bfloat162_rn(float2{lo, hi});
    return *reinterpret_cast<unsigned int*>(&b);
}

// runtime index-width detect: int64 inputs (values < 2^31) have all-zero odd
// int32 slots; random int32 node ids can't have 64 consecutive zero odd slots.
__device__ __forceinline__ int detect_w(const int* __restrict__ ei) {
    int lane = threadIdx.x & 63;
    int v = ei[2 * lane + 1];
    return (__ballot(v != 0) == 0ULL) ? 1 : 0;
}
__device__ __forceinline__ int ld_idx(const int* __restrict__ p, long long i, int w) {
    return w ? p[2 * i] : p[i];
}

// ---------------- prep: transposes + graph starts + cursors + zero-row ----------------
__global__ void __launch_bounds__(256) k_prep(
    const float* __restrict__ w1, const float* __restrict__ w2,
    unsigned short* __restrict__ wt1, unsigned short* __restrict__ wt2,
    const int* __restrict__ ei, const int* __restrict__ batch,
    int* __restrict__ gstart, int* __restrict__ bcursor,
    unsigned short* __restrict__ xws)
{
    int b = blockIdx.x, t = threadIdx.x;
    if (b < 128) {                       // both 128x128 transposes (fp32 -> bf16)
        int idx = b * 256 + t;           // 0..32767
        int which = idx >> 14, r = idx & 16383;
        int k = r >> 7, j = r & 127;
        const float* w = which ? w2 : w1;
        unsigned short* wt = which ? wt2 : wt1;
        wt[j * 128 + k] = f2b(w[k * 128 + j]);
    } else if (b < 128 + NSTARTB) {      // graph start offsets (batch sorted)
        int w = detect_w(ei);
        int i = (b - 128) * 256 + t;
        if (i < NN) {
            int bb = ld_idx(batch, i, w);
            int prev = (i == 0) ? -1 : ld_idx(batch, i - 1, w);
            for (int g = prev + 1; g <= bb; ++g) gstart[g] = i;
            if (i == NN - 1)
                for (int g = bb + 1; g <= NGRAPH; ++g) gstart[g] = NN;
        }
    } else {                             // cursor init + zero row NN of xws
        int i = (b - 128 - NSTARTB) * 256 + t;
        if (i < NBKT) bcursor[i] = i * CAP;
        if (b == 128 + NSTARTB && t < FDIM) xws[(size_t)NN * FDIM + t] = 0;
    }
}

// ---------------- scatter edges into fixed-stride dst-buckets (RANKED writes) --------
// record = src (17 bits) | (dst & 255) << 17
__global__ void __launch_bounds__(512) k_scat(const int* __restrict__ ei,
                                              int* __restrict__ bcursor,
                                              unsigned int* __restrict__ rec) {
    __shared__ int hist[NBKT];
    __shared__ int gbase[NBKT];
    __shared__ int lcur[NBKT];
    int t = threadIdx.x;
    int w = detect_w(ei);
    for (int i = t; i < NBKT; i += 512) hist[i] = 0;
    __syncthreads();
    long long e0 = (long long)blockIdx.x * SCHUNK;
    unsigned int myrec[8];
    int mybkt[8];
    #pragma unroll
    for (int j = 0; j < 8; ++j) {
        long long e = e0 + j * 512 + t;
        if (e < NE) {
            int s = ld_idx(ei, e, w);
            int d = ld_idx(ei, NE + e, w);
            mybkt[j] = d >> 8;
            myrec[j] = (unsigned int)s | ((unsigned int)(d & 255) << 17);
            atomicAdd(&hist[mybkt[j]], 1);
        } else mybkt[j] = -1;
    }
    __syncthreads();
    for (int i = t; i < NBKT; i += 512) {
        int c = hist[i];
        gbase[i] = c ? atomicAdd(&bcursor[i], c) : 0;
        lcur[i] = 0;
    }
    __syncthreads();
    #pragma unroll
    for (int j = 0; j < 8; ++j) {
        int b = mybkt[j];
        if (b >= 0) {
            int r = atomicAdd(&lcur[b], 1);
            int p = gbase[b] + r;
            if (p < (b + 1) * CAP) rec[p] = myrec[j];   // overflow guard (~never)
        }
    }
}

// ---------------- per-bucket counting sort -> padded csr + odeg + dinv ---------------
// csr holds BYTE offsets (src*256). Layout padded to 16-slot multiples per node;
// odeg.y = 4-padded REAL count (deg + self, rounded up to x4), so k_agg processes
// at most 3 sentinel slots per node. Self-loop slot at index deg; all other pad
// slots point at zero row NN.
__global__ void __launch_bounds__(256) k_bucket(const unsigned int* __restrict__ rec,
                                                const int* __restrict__ bcursor,
                                                int* __restrict__ csr,
                                                int2* __restrict__ odeg,
                                                float* __restrict__ dinv) {
    __shared__ unsigned int rbuf[CAP];
    __shared__ int srcout[PCAP];
    __shared__ int hist[256], scn[256], cur[256];
    int b = blockIdx.x, t = threadIdx.x;
    int rbase = b * CAP;
    int cnt = bcursor[b] - rbase;
    if (cnt > CAP) cnt = CAP;
    hist[t] = 0;
    __syncthreads();
    for (int j = t; j < cnt; j += 256) {
        unsigned int r = __builtin_nontemporal_load(&rec[rbase + j]);
        rbuf[j] = r;
        atomicAdd(&hist[r >> 17], 1);
    }
    for (int j = t; j < PCAP; j += 256) srcout[j] = NN << 8;   // sentinel = zero row
    __syncthreads();
    int node = (b << 8) + t;
    int v = hist[t];
    int pv = (node < NN) ? ((v + 16) & ~15) : 0;   // layout: +1 self slot, pad to 16
    scn[t] = pv;
    __syncthreads();
    for (int o = 1; o < 256; o <<= 1) {
        int tv = (t >= o) ? scn[t - o] : 0;
        __syncthreads();
        scn[t] += tv;
        __syncthreads();
    }
    int pexcl = scn[t] - pv;
    cur[t] = pexcl;
    int obase = b * PCAP;
    if (node < NN) {
        odeg[node] = make_int2(obase + pexcl, (v + 4) & ~3);  // 4-padded count incl self
        dinv[node] = rsqrtf((float)(v + 1));
        srcout[pexcl + v] = node << 8;                        // self-loop slot
    }
    __syncthreads();
    for (int j = t; j < cnt; j += 256) {
        unsigned int r = rbuf[j];
        int p = atomicAdd(&cur[r >> 17], 1);
        srcout[p] = (int)(r & 0x1FFFFu) << 8;        // pre-scaled byte offset
    }
    __syncthreads();
    int total = scn[255];
    for (int j = t; j < total; j += 256) csr[obase + j] = srcout[j];
}

// ---------------- GEMM: OUT[v][:] = bf16(dinv[v] * (X[v][:] @ W)) ----------------
#define LWS 136   // padded LDS row stride (bf16 elems)
template <bool BF16IN>
__global__ void __launch_bounds__(256) k_gemm(
    const void* __restrict__ Xv,            // [NN,128] fp32 or bf16
    const unsigned short* __restrict__ WT,  // [128,128] bf16, WT[j][k] = W[k][j]
    const float* __restrict__ dinv,
    unsigned short* __restrict__ OUT)       // [NN,128] bf16, scaled by dinv[row]
{
    __shared__ unsigned short lw[128 * LWS];
    int tid = threadIdx.x;
    for (int it = 0; it < 8; ++it) {
        int vidx = it * 256 + tid;
        int j = vidx >> 4, kc = vidx & 15;
        ushort8 v = *(const ushort8*)(WT + j * 128 + kc * 8);
        *(ushort8*)(&lw[j * LWS + kc * 8]) = v;
    }
    __syncthreads();

    int wave = tid >> 6, lane = tid & 63;
    int quad = lane >> 4, n16 = lane & 15;
    int row0 = (blockIdx.x * 4 + wave) * 16;
    if (row0 >= NN) return;   // NN % 16 == 0

    f32x4 acc[8];
    for (int ct = 0; ct < 8; ++ct) acc[ct] = (f32x4){0.f, 0.f, 0.f, 0.f};

    const int arow = row0 + n16;
    for (int kk = 0; kk < 4; ++kk) {
        short8 a;
        if (BF16IN) {
            a = *(const short8*)((const unsigned short*)Xv + (size_t)arow * 128 + kk * 32 + quad * 8);
        } else {
            const float* ap = (const float*)Xv + (size_t)arow * 128 + kk * 32 + quad * 8;
            float4 a01 = *(const float4*)(ap);
            float4 a23 = *(const float4*)(ap + 4);
            uint4 P;
            P.x = cvt2(a01.x, a01.y);
            P.y = cvt2(a01.z, a01.w);
            P.z = cvt2(a23.x, a23.y);
            P.w = cvt2(a23.z, a23.w);
            a = *(short8*)&P;
        }
        for (int ct = 0; ct < 8; ++ct) {
            short8 b = *(const short8*)(&lw[(ct * 16 + n16) * LWS + kk * 32 + quad * 8]);
            acc[ct] = __builtin_amdgcn_mfma_f32_16x16x32_bf16(a, b, acc[ct], 0, 0, 0);
        }
    }
    // C/D layout: col = lane&15, row = quad*4 + reg
    for (int r = 0; r < 4; ++r) {
        int row = row0 + quad * 4 + r;
        float dv = dinv[row];
        for (int ct = 0; ct < 8; ++ct)
            OUT[(size_t)row * 128 + ct * 16 + n16] = f2b(acc[ct][r] * dv);
    }
}

// ---------------- aggregation: 4-granular padded csr, per-group loop bound ----------
// Lane = (edge slot group g 0..3, feature chunk f 0..15). Group g covers slots
// {j+4g .. j+4g+3 : j = 0,16,32,...} while j+4g < pdeg4. Trip counts differ by at
// most 1 between groups (exec-mask divergence); mean slots processed ~20 vs 32 for
// the 16-granular version (-37% gather instructions).
__device__ __forceinline__ void acc8(f32x2* a2, uint4 q) {
    a2[0] += (f32x2){blo(q.x), bhi(q.x)};
    a2[1] += (f32x2){blo(q.y), bhi(q.y)};
    a2[2] += (f32x2){blo(q.z), bhi(q.z)};
    a2[3] += (f32x2){blo(q.w), bhi(q.w)};
}

__global__ void __launch_bounds__(256) k_agg(
    const unsigned short* __restrict__ XWS,   // [NN+1,128] bf16, row NN = zeros
    const int* __restrict__ csr,              // padded byte-offsets (src*256)
    const int2* __restrict__ odeg,            // {csr offset, 4-padded count incl self}
    const float* __restrict__ dinv,
    const float* __restrict__ bias,           // 128 fp32
    unsigned short* __restrict__ H)           // [NN,128] bf16
{
    int wave = threadIdx.x >> 6, lane = threadIdx.x & 63;
    int v = blockIdx.x * 4 + wave;             // NN % 4 == 0
    int g = lane >> 4, f = lane & 15;          // edge slot group, feature chunk (8 feats)
    int2 od = odeg[v];
    int beg = od.x, pdeg4 = od.y;
    const char* xb = (const char*)XWS;
    unsigned fo = (unsigned)(f * 16);
    const int* cp = csr + beg + 4 * g;
    int lim = pdeg4 - 4 * g;                   // my group's loop bound

    f32x2 a2[4];
    a2[0] = (f32x2){0.f, 0.f}; a2[1] = (f32x2){0.f, 0.f};
    a2[2] = (f32x2){0.f, 0.f}; a2[3] = (f32x2){0.f, 0.f};

    for (int j = 0; j < lim; j += 16) {
        int4 c = *(const int4*)(cp + j);
        uint4 q0 = *(const uint4*)(xb + ((unsigned)c.x + fo));
        uint4 q1 = *(const uint4*)(xb + ((unsigned)c.y + fo));
        uint4 q2 = *(const uint4*)(xb + ((unsigned)c.z + fo));
        uint4 q3 = *(const uint4*)(xb + ((unsigned)c.w + fo));
        acc8(a2, q0);
        acc8(a2, q1);
        acc8(a2, q2);
        acc8(a2, q3);
    }
    #pragma unroll
    for (int i = 0; i < 4; ++i) {
        a2[i].x += __shfl_xor(a2[i].x, 16);
        a2[i].y += __shfl_xor(a2[i].y, 16);
        a2[i].x += __shfl_xor(a2[i].x, 32);
        a2[i].y += __shfl_xor(a2[i].y, 32);
    }
    if (g == 0) {
        float dv = dinv[v];
        float4 b0 = *(const float4*)(bias + f * 8);
        float4 b1 = *(const float4*)(bias + f * 8 + 4);
        uint4 o;
        o.x = cvt2(fmaxf(fmaf(a2[0].x, dv, b0.x), 0.f), fmaxf(fmaf(a2[0].y, dv, b0.y), 0.f));
        o.y = cvt2(fmaxf(fmaf(a2[1].x, dv, b0.z), 0.f), fmaxf(fmaf(a2[1].y, dv, b0.w), 0.f));
        o.z = cvt2(fmaxf(fmaf(a2[2].x, dv, b1.x), 0.f), fmaxf(fmaf(a2[2].y, dv, b1.y), 0.f));
        o.w = cvt2(fmaxf(fmaf(a2[3].x, dv, b1.z), 0.f), fmaxf(fmaf(a2[3].y, dv, b1.w), 0.f));
        *(uint4*)(H + (size_t)v * FDIM + f * 8) = o;
    }
}

// ---------------- fused global mean pool + classifier (512 thr, 8-way stripe) --------
__global__ void __launch_bounds__(512) k_poolcls(
    const unsigned short* __restrict__ H, const int* __restrict__ gstart,
    const float* __restrict__ wc, const float* __restrict__ bc,
    float* __restrict__ out)
{
    __shared__ float red[1024];
    __shared__ float pl[FDIM];
    int g = blockIdx.x;
    int t = threadIdx.x;
    int pair = t & 63;
    int seg = t >> 6;                       // 0..7
    int beg = gstart[g], end = gstart[g + 1];
    float a0 = 0.f, a1 = 0.f;
    for (int i = beg + seg; i < end; i += 8) {
        unsigned int q = *(const unsigned int*)(H + (size_t)i * FDIM + 2 * pair);
        a0 += blo(q); a1 += bhi(q);
    }
    red[t] = a0; red[512 + t] = a1;
    __syncthreads();
    if (seg == 0) {
        float s0 = 0.f, s1 = 0.f;
        #pragma unroll
        for (int k = 0; k < 8; ++k) {
            s0 += red[pair + 64 * k];
            s1 += red[512 + pair + 64 * k];
        }
        float inv = 1.f / fmaxf((float)(end - beg), 1.f);
        pl[2 * pair] = s0 * inv;
        pl[2 * pair + 1] = s1 * inv;
    }
    __syncthreads();
    if (t < 256) {
        int o = t & 15, fs = t >> 4;
        float acc = 0.f;
        #pragma unroll
        for (int k = 0; k < 8; ++k)
            acc += pl[fs * 8 + k] * wc[(fs * 8 + k) * ODIM + o];
        red[t] = acc;
    }
    __syncthreads();
    if (t < 16) {
        float s = bc[t];
        #pragma unroll
        for (int k = 0; k < 16; ++k) s += red[k * 16 + t];
        out[g * ODIM + t] = s;
    }
}

extern "C" void kernel_launch(void* const* d_in, const int* in_sizes, int n_in,
                              void* d_out, int out_size, void* d_ws, size_t ws_size,
                              hipStream_t stream) {
    const float* x   = (const float*)d_in[0];
    const int* ei    = (const int*)d_in[1];
    const int* batch = (const int*)d_in[2];
    const float* w1  = (const float*)d_in[3];
    const float* b1  = (const float*)d_in[4];
    const float* w2  = (const float*)d_in[5];
    const float* b2  = (const float*)d_in[6];
    const float* wc  = (const float*)d_in[7];
    const float* bc  = (const float*)d_in[8];
    float* out = (float*)d_out;

    char* ws = (char*)d_ws;
    size_t off = 0;
    auto alloc = [&](size_t bytes) -> void* {
        off = (off + 255) & ~(size_t)255;
        void* p = ws + off;
        off += bytes;
        return p;
    };
    int*   bcursor = (int*)alloc(NBKT * 4);
    int2*  odeg    = (int2*)alloc((size_t)NN * 8);
    float* dinv    = (float*)alloc(NN * 4);
    int*   gstart  = (int*)alloc((NGRAPH + 1) * 4);
    unsigned int* rec = (unsigned int*)alloc((size_t)NBKT * CAP * 4);
    int*   csr     = (int*)alloc((size_t)NBKT * PCAP * 4 + 256);   // padded stride
    unsigned short* wt1 = (unsigned short*)alloc(128 * 128 * 2);
    unsigned short* wt2 = (unsigned short*)alloc(128 * 128 * 2);
    unsigned short* xws = (unsigned short*)alloc((size_t)(NN + 1) * FDIM * 2);  // +zero row
    unsigned short* h   = (unsigned short*)alloc((size_t)NN * FDIM * 2);

    k_prep<<<128 + NSTARTB + 2, 256, 0, stream>>>(w1, w2, wt1, wt2, ei, batch, gstart, bcursor, xws);
    k_scat<<<NSCAT, 512, 0, stream>>>(ei, bcursor, rec);
    k_bucket<<<NBKT, 256, 0, stream>>>(rec, bcursor, csr, odeg, dinv);

    // layer 1
    k_gemm<false><<<(NN / 16 + 3) / 4, 256, 0, stream>>>(x, wt1, dinv, xws);
    k_agg<<<NN / 4, 256, 0, stream>>>(xws, csr, odeg, dinv, b1, h);
    // layer 2
    k_gemm<true><<<(NN / 16 + 3) / 4, 256, 0, stream>>>(h, wt2, dinv, xws);
    k_agg<<<NN / 4, 256, 0, stream>>>(xws, csr, odeg, dinv, b2, h);
    // pool + classify (fused)
    k_poolcls<<<NGRAPH, 512, 0, stream>>>(h, gstart, wc, bc, out);
}